// Round 10
// baseline (2742.448 us; speedup 1.0000x reference)
//
#include <hip/hip_runtime.h>

#ifndef M_PI
#define M_PI 3.14159265358979323846
#endif

#define T_DATA 20000
#define E_NO_C 2000
#define I_NO_C 500
#define SUB 16
#define TNO 200
#define NGRP 5000   // 4-step groups

typedef float v2f __attribute__((ext_vector_type(2)));

// Raw workgroup barrier: LDS ordering only (lgkmcnt), vmem stays IN FLIGHT across it.
// This is the whole point of R10 — __syncthreads would drain vmcnt(0) per wave.
#define BAR() asm volatile("s_waitcnt lgkmcnt(0)\n\ts_barrier" ::: "memory")

// ---------------- Kernel A: filter kernels (e, i, spk, hist) -> d_out[320000..] ----------------
__global__ void filters_k(const float* __restrict__ Tau_e, const float* __restrict__ Tau_i,
                          const float* __restrict__ W_e,  const float* __restrict__ W_i,
                          const float* __restrict__ D_e,  const float* __restrict__ D_i,
                          const float* __restrict__ Tau_spk, const float* __restrict__ W_spk,
                          const float* __restrict__ W_hist,
                          float* __restrict__ filt_out) {
  int id = blockIdx.x * blockDim.x + threadIdx.x;
  if (id >= 64 * TNO) return;
  int r = id / TNO, x = id % TNO;
  int s = r & 15, kind = r >> 4;
  double xd = (double)x;
  double val;
  if (kind == 0) {
    double te = xd - exp((double)D_e[s]); te = te > 0.0 ? te : 0.0;
    double tt = te / exp((double)Tau_e[s]);
    val = tt * exp(-tt) * exp((double)W_e[s]);
  } else if (kind == 1) {
    double ti = xd - exp((double)D_i[s]); ti = ti > 0.0 ? ti : 0.0;
    double tt = ti / exp((double)Tau_i[s]);
    val = -tt * exp(-tt) * exp((double)W_i[s]);
  } else if (kind == 2) {
    double tt = xd / exp((double)Tau_spk[s]);
    val = tt * exp(-tt) * exp((double)W_spk[s]);
  } else {
    double raw = 4.0 * log(xd + 1.0);
    double acc = 0.0;
    for (int i = 0; i < 16; ++i) {
      double phi = (M_PI / 2.0) * (double)i;
      double b = (raw < phi - M_PI || raw > phi + M_PI) ? 0.0
                                                        : (0.5 * cos(raw - phi) + 0.5);
      acc += (double)W_hist[s * 16 + i] * b;
    }
    val = acc;
  }
  filt_out[id] = (float)val;
}

// ---------------- Kernel B: syn = S @ C^T, C staged in LDS tiles ----------------
#define ETILE 500
__global__ __launch_bounds__(256) void synmm_k(const float* __restrict__ S,
                                               const float* __restrict__ C,
                                               float* __restrict__ out, int E) {
  __shared__ __align__(16) float Cs[16][ETILE];
  int tid = threadIdx.x;
  int s = tid & 15, tt = tid >> 4;
  long t = (long)blockIdx.x * 16 + tt;
  const float* Srow = S + t * E;
  float acc = 0.f;
  for (int tb = 0; tb < E; tb += ETILE) {
    __syncthreads();
    for (int i = tid; i < 16 * ETILE; i += 256) {
      int s2 = i / ETILE, k2 = i - s2 * ETILE;
      Cs[s2][k2] = C[(long)s2 * E + tb + k2];
    }
    __syncthreads();
    const float* Crow = &Cs[s][0];
    const float* Sp = Srow + tb;
#pragma unroll 2
    for (int e = 0; e < ETILE; e += 4) {
      float4 a = *(const float4*)(Sp + e);
      float4 c = *(const float4*)(Crow + e);
      acc = fmaf(a.x, c.x, acc); acc = fmaf(a.y, c.y, acc);
      acc = fmaf(a.z, c.z, acc); acc = fmaf(a.w, c.w, acc);
    }
  }
  out[t * 16 + s] = acc;
}

// ---------------- Kernel C: causal depthwise conv + Theta, [t][s] layout ----------------
__global__ void conv_k(const float* __restrict__ syn_e, const float* __restrict__ syn_i,
                       const float* __restrict__ filt, const float* __restrict__ Theta,
                       float* __restrict__ synTh) {
  __shared__ float ek[16][201];
  __shared__ float ik[16][201];
  int tid = threadIdx.x;
  for (int idx = tid; idx < 16 * TNO; idx += 256) {
    ek[idx / TNO][idx % TNO] = filt[idx];
    ik[idx / TNO][idx % TNO] = filt[16 * TNO + idx];
  }
  __syncthreads();
  int s = tid & 15, tt = tid >> 4;
  int t = blockIdx.x * 16 + tt;
  float acc = Theta[s];
  if (t >= TNO) {
#pragma unroll 4
    for (int j = 0; j < TNO; ++j) {
      int u = t - 1 - j;
      acc += ek[s][j] * syn_e[u * 16 + s] + ik[s][j] * syn_i[u * 16 + s];
    }
  } else {
    for (int j = 0; j < t; ++j) {
      int u = t - 1 - j;
      acc += ek[s][j] * syn_e[u * 16 + s] + ik[s][j] * syn_i[u * 16 + s];
    }
  }
  synTh[t * 16 + s] = acc;
}

// ---------------- Kernel D: 9-wave pipeline, raw barriers, pipelined io ----------------
// Identical delay partition to R9 (verified): chain d=1; pend d<=3 in-group; carry S
// hidx 1..6; carry2 P hidx K+4..K+7; near (lag-2) hidx K+8..K+11; far (lag-3) K+12..199.
// New: in-loop barriers are raw (no vmcnt drain); io synTh loads pipelined 4 iters deep
// (load at window n -> ds_write at window n+4); synStage 4 buffers (16 groups).
__global__ __launch_bounds__(576, 1) void scan9_k(const float* __restrict__ synTh,
                                                  const float* __restrict__ filt,
                                                  const float* __restrict__ C_den,
                                                  const float* __restrict__ Tau_spk,
                                                  const float* __restrict__ W_spk,
                                                  float* __restrict__ spk_out) {
  __shared__ __align__(16) float ring[16][452];       // [s][pos], mirror pos+256 for pos<192
  __shared__ __align__(16) float oPartR[3][6][16][4]; // [slot][farwave][s][K]
  __shared__ __align__(16) float farTot[2][16][4];
  __shared__ __align__(16) float nearBuf[2][16][4];
  __shared__ __align__(16) float synStage[4][4][16][20]; // [buf][g&3][s][K(+pad)]
  const int tid = threadIdx.x;
  const int widx = tid >> 6;
  const int l = tid & 63;
  const int s = l & 15, q = l >> 4;

  for (int i = tid; i < 16 * 452; i += 576) (&ring[0][0])[i] = 0.f;
  for (int i = tid; i < 3 * 6 * 16 * 4; i += 576) (&oPartR[0][0][0][0])[i] = 0.f;
  for (int i = tid; i < 2 * 16 * 4; i += 576) {
    (&farTot[0][0][0])[i] = 0.f;
    (&nearBuf[0][0][0])[i] = 0.f;
  }
  __syncthreads();
  float4 pipeReg;   // io pipeline register (4 future groups / window)
  if (widx == 2) {  // io: preload synTh groups 0..7, issue loads for 8..11
#pragma unroll
    for (int b2 = 0; b2 < 2; ++b2) {
      int e0 = b2 * 256 + 4 * l;
      float4 v = *(const float4*)&synTh[e0];
      int t0 = e0 >> 4, s0 = e0 & 15;
      int g = t0 >> 2, K = t0 & 3;
      synStage[(g >> 2) & 3][g & 3][s0 + 0][K] = v.x;
      synStage[(g >> 2) & 3][g & 3][s0 + 1][K] = v.y;
      synStage[(g >> 2) & 3][g & 3][s0 + 2][K] = v.z;
      synStage[(g >> 2) & 3][g & 3][s0 + 3][K] = v.w;
    }
    pipeReg = *(const float4*)&synTh[8 * 64 + 4 * l];   // groups 8..11
  }
  __syncthreads();

  if (widx == 0) {
    // ================= scan wave (no global memory, no vmem at barriers) =================
    const float* hrow = filt + (48 + s) * TNO;
    float hk[11];
#pragma unroll
    for (int i = 0; i < 11; ++i) hk[i] = hrow[i];

    float t0v = Tau_spk[0], w0v = W_spk[0];
    bool okrow = (Tau_spk[s] == t0v) && (W_spk[s] == w0v);
    unsigned cd = 0u;
#pragma unroll
    for (int j = 0; j < 16; ++j) {
      float cv = C_den[s * 16 + j];
      okrow = okrow && (cv == 0.f || cv == 1.f);
      cd |= (cv != 0.f) ? (1u << j) : 0u;
    }
    const bool uni = (bool)__all((int)okrow);

    const double tau  = exp((double)Tau_spk[s]);
    const double aa   = exp(-1.0 / tau);
    const double c2a  = exp((double)W_spk[s]) * aa / tau;  // K[d]=C(d-1)a^(d-1), C=w/tau
    const double twoa = 2.0 * aa;
    const double na2  = -aa * aa;

    double twoa4[4], na24[4], c2a4[4], yd0a[4], yd1a[4];
    float cden4[4];
#pragma unroll
    for (int r = 0; r < 4; ++r) {
      int j = 4 * q + r;
      double tj = exp((double)Tau_spk[j]);
      double aj = exp(-1.0 / tj);
      twoa4[r] = 2.0 * aj; na24[r] = -aj * aj;
      c2a4[r]  = exp((double)W_spk[j]) * aj / tj;
      yd0a[r] = 0.0; yd1a[r] = 0.0;
      cden4[r] = C_den[s * 16 + j];
    }

    double zA = 0.0, zB = 0.0;
    float mixu = 0.f, mix1 = 0.f;
    float P0 = 0.f, P1 = 0.f, P2 = 0.f, P3 = 0.f;   // prev group's spikes
    float sgPrev = 0.f;

    float4 syn0 = *(const float4*)&synStage[0][0][s][0];
    float oc0 = syn0.x, oc1 = syn0.y, oc2 = syn0.z, oc3 = syn0.w;

#define STEP(SGD, PRE, SGOUT)                                                 \
    {                                                                         \
      float sub = fmaf(hk[0], (SGD), (PRE));                                  \
      unsigned long long bal = __ballot(sub > 0.f);                           \
      float sg = sub > 0.f ? 1.f : 0.f;                                       \
      unsigned mk = (unsigned)bal & 0xFFFFu;                                  \
      if (uni) {                                                              \
        double zc = fma(twoa, zB, fma(na2, zA, c2a * (double)__popc(mk & cd))); \
        zA = zB; zB = zc;                                                     \
        mixu = (float)zA;                                                     \
      } else {                                                                \
        float p = 0.f;                                                        \
        _Pragma("unroll")                                                     \
        for (int r = 0; r < 4; ++r) {                                         \
          double xr = (double)((mk >> (4 * q + r)) & 1u);                     \
          double y2 = fma(twoa4[r], yd1a[r], fma(na24[r], yd0a[r], c2a4[r] * xr)); \
          yd0a[r] = yd1a[r]; yd1a[r] = y2;                                    \
          p = fmaf(cden4[r], (float)y2, p);                                   \
        }                                                                     \
        p += __shfl_xor(p, 16); p += __shfl_xor(p, 32);                       \
        float mixn = mix1; mix1 = p;                                          \
        mixu = mixn;                                                          \
      }                                                                       \
      (SGOUT) = sg;                                                           \
    }

    for (int n = 0; n < NGRP; ++n) {
      const int gn = n + 1;
      float4 farT  = *(const float4*)&farTot[gn & 1][s][0];
      float4 nearT = *(const float4*)&nearBuf[gn & 1][s][0];
      float4 synT  = *(const float4*)&synStage[(gn >> 2) & 3][gn & 3][s][0];

      float S0, S1, S2, S3;
      STEP(sgPrev, oc0 + mixu, S0)
      float pend2 = hk[1] * S0;
      float pend3 = hk[2] * S0;
      STEP(S0, oc1 + mixu, S1)
      pend3 = fmaf(hk[1], S1, pend3);
      STEP(S1, (oc2 + mixu) + pend2, S2)
      STEP(S2, (oc3 + mixu) + pend3, S3)

      if (l < 16) {
        int u = (4 * n) & 255;
        float4 w0; w0.x = S0; w0.y = S1; w0.z = S2; w0.w = S3;
        *(float4*)&ring[s][u] = w0;
        if (u < 192) *(float4*)&ring[s][u + 256] = w0;
      }

      float c0 = fmaf(hk[1], S2, fmaf(hk[2], S1, hk[3] * S0));
      float c1 = fmaf(hk[1], S3, fmaf(hk[2], S2, fmaf(hk[3], S1, hk[4] * S0)));
      float c2 = fmaf(hk[2], S3, fmaf(hk[3], S2, fmaf(hk[4], S1, hk[5] * S0)));
      float c3 = fmaf(hk[3], S3, fmaf(hk[4], S2, fmaf(hk[5], S1, hk[6] * S0)));
      float cc0 = fmaf(hk[7], P0, fmaf(hk[6], P1, fmaf(hk[5], P2, hk[4] * P3)));
      float cc1 = fmaf(hk[8], P0, fmaf(hk[7], P1, fmaf(hk[6], P2, hk[5] * P3)));
      float cc2 = fmaf(hk[9], P0, fmaf(hk[8], P1, fmaf(hk[7], P2, hk[6] * P3)));
      float cc3 = fmaf(hk[10], P0, fmaf(hk[9], P1, fmaf(hk[8], P2, hk[7] * P3)));

      oc0 = ((farT.x + nearT.x) + (synT.x + c0)) + cc0;
      oc1 = ((farT.y + nearT.y) + (synT.y + c1)) + cc1;
      oc2 = ((farT.z + nearT.z) + (synT.z + c2)) + cc2;
      oc3 = ((farT.w + nearT.w) + (synT.w + c3)) + cc3;

      P0 = S0; P1 = S1; P2 = S2; P3 = S3;
      sgPrev = S3;
      BAR();
    }
#undef STEP
  } else if (widx == 1) {
    // ================= near + reduce wave =================
    const float* hrow = filt + (48 + s) * TNO;
    float hk[15];
#pragma unroll
    for (int i = 0; i < 15; ++i) hk[i] = hrow[i];

    for (int n = 0; n < NGRP; ++n) {
      int We = (4 * n - 1) & 255;
      if (We < 191) We += 256;
      float4 v = *(const float4*)&ring[s][We - 3];
      float nr0 = fmaf(hk[11], v.x, fmaf(hk[10], v.y, fmaf(hk[9],  v.z, hk[8]  * v.w)));
      float nr1 = fmaf(hk[12], v.x, fmaf(hk[11], v.y, fmaf(hk[10], v.z, hk[9]  * v.w)));
      float nr2 = fmaf(hk[13], v.x, fmaf(hk[12], v.y, fmaf(hk[11], v.z, hk[10] * v.w)));
      float nr3 = fmaf(hk[14], v.x, fmaf(hk[13], v.y, fmaf(hk[12], v.z, hk[11] * v.w)));
      if (l < 16) {
        float4 nv; nv.x = nr0; nv.y = nr1; nv.z = nr2; nv.w = nr3;
        *(float4*)&nearBuf[(n + 2) & 1][s][0] = nv;
      }
      const int slot = (n + 2) % 3;
      float4 a0 = *(const float4*)&oPartR[slot][0][s][0];
      float4 a1 = *(const float4*)&oPartR[slot][1][s][0];
      float4 a2 = *(const float4*)&oPartR[slot][2][s][0];
      float4 a3 = *(const float4*)&oPartR[slot][3][s][0];
      float4 a4 = *(const float4*)&oPartR[slot][4][s][0];
      float4 a5 = *(const float4*)&oPartR[slot][5][s][0];
      float4 acc;
      acc.x = ((a0.x + a1.x) + (a2.x + a3.x)) + (a4.x + a5.x);
      acc.y = ((a0.y + a1.y) + (a2.y + a3.y)) + (a4.y + a5.y);
      acc.z = ((a0.z + a1.z) + (a2.z + a3.z)) + (a4.z + a5.z);
      acc.w = ((a0.w + a1.w) + (a2.w + a3.w)) + (a4.w + a5.w);
      if (l < 16) *(float4*)&farTot[(n + 2) & 1][s][0] = acc;
      BAR();
    }
  } else if (widx == 2) {
    // ================= io wave: spk_out (batch 8), synStage (pipelined 4 deep) =========
    for (int n = 0; n < NGRP; ++n) {
      if ((n & 3) == 2) {
        // ds_write groups n+6..n+9 from pipeReg (loaded 4 iters ago -> vmcnt wait free)
        int gW = n + 6;
        if (gW < NGRP) {
          int e0 = gW * 64 + 4 * l;
          float4 v = pipeReg;
          int t0 = e0 >> 4, s0 = e0 & 15;
          int g = t0 >> 2, K = t0 & 3;
          int buf = (g >> 2) & 3;
          synStage[buf][g & 3][s0 + 0][K] = v.x;
          synStage[buf][g & 3][s0 + 1][K] = v.y;
          synStage[buf][g & 3][s0 + 2][K] = v.z;
          synStage[buf][g & 3][s0 + 3][K] = v.w;
        }
        // issue loads for groups n+10..n+13 (stay in flight across raw barriers)
        int e1 = (n + 10) * 64 + 4 * l;
        if (e1 + 3 < 64 * NGRP) pipeReg = *(const float4*)&synTh[e1];
        else { pipeReg.x = 0.f; pipeReg.y = 0.f; pipeReg.z = 0.f; pipeReg.w = 0.f; }
      }
      if ((n & 7) == 0 && n > 0) {
        int We = (4 * n - 1) & 255;
        if (We < 191) We += 256;
        int base = We - 31;                   // times 4n-32..4n-1
#pragma unroll
        for (int r = 0; r < 2; ++r) {
          int e = 64 * (n - 8) + 256 * r + 4 * l;
          int t0 = e >> 4, s0 = e & 15;
          int pos = base + (t0 - 4 * (n - 8));
          float4 w;
          w.x = ring[s0 + 0][pos]; w.y = ring[s0 + 1][pos];
          w.z = ring[s0 + 2][pos]; w.w = ring[s0 + 3][pos];
          *(float4*)&spk_out[e] = w;
        }
      }
      BAR();
    }
    {   // tail: groups NGRP-8..NGRP-1
      int n = NGRP;
      int We = (4 * n - 1) & 255;
      if (We < 191) We += 256;
      int base = We - 31;
#pragma unroll
      for (int r = 0; r < 2; ++r) {
        int e = 64 * (n - 8) + 256 * r + 4 * l;
        int t0 = e >> 4, s0 = e & 15;
        int pos = base + (t0 - 4 * (n - 8));
        float4 w;
        w.x = ring[s0 + 0][pos]; w.y = ring[s0 + 1][pos];
        w.z = ring[s0 + 2][pos]; w.w = ring[s0 + 3][pos];
        *(float4*)&spk_out[e] = w;
      }
    }
  } else {
    // ================= far waves f=0..5: group n+3, hidx >= K+12 =================
    const int f = widx - 3;
    const int b = 4 * f + q;                 // chunk 0..23, window offsets 8b..8b+7
    const float* hrow = filt + (48 + s) * TNO;
    float ca[11];
#pragma unroll
    for (int m = 0; m < 11; ++m) {
      int hidx = 196 - 8 * b + m;
      ca[m] = (hidx <= 199) ? hrow[hidx] : 0.f;
    }
    v2f pr[11];
    pr[0].x = 0.f; pr[0].y = 0.f;
#pragma unroll
    for (int m = 1; m < 11; ++m) { pr[m].x = ca[m]; pr[m].y = ca[m - 1]; }

    for (int n = 0; n < NGRP; ++n) {
      int We = (4 * n - 1) & 255;
      if (We < 191) We += 256;
      const int Ws = We - 191;
      const float4* rp = (const float4*)&ring[s][Ws + 8 * b];
      float4 V0 = rp[0], V1 = rp[1];
      v2f p01, p23, p45, p67;
      p01.x = V0.x; p01.y = V0.y; p23.x = V0.z; p23.y = V0.w;
      p45.x = V1.x; p45.y = V1.y; p67.x = V1.z; p67.y = V1.w;
      float o[4];
#pragma unroll
      for (int K = 0; K < 4; ++K) {
        v2f a = pr[7 + K] * p01;
        a += pr[5 + K] * p23;
        a += pr[3 + K] * p45;
        a += pr[1 + K] * p67;
        float vv = a.x + a.y;
        vv += __shfl_xor(vv, 16);
        vv += __shfl_xor(vv, 32);
        o[K] = vv;
      }
      if (l < 16) {
        float4 ov; ov.x = o[0]; ov.y = o[1]; ov.z = o[2]; ov.w = o[3];
        *(float4*)&oPartR[n % 3][f][s][0] = ov;
      }
      BAR();
    }
  }
}

extern "C" void kernel_launch(void* const* d_in, const int* in_sizes, int n_in,
                              void* d_out, int out_size, void* d_ws, size_t ws_size,
                              hipStream_t stream) {
  const float* S_e     = (const float*)d_in[0];
  const float* S_i     = (const float*)d_in[1];
  const float* C_den   = (const float*)d_in[2];
  const float* C_syn_e = (const float*)d_in[3];
  const float* C_syn_i = (const float*)d_in[4];
  const float* Tau_e   = (const float*)d_in[5];
  const float* Tau_i   = (const float*)d_in[6];
  const float* W_e     = (const float*)d_in[7];
  const float* W_i     = (const float*)d_in[8];
  const float* D_e     = (const float*)d_in[9];
  const float* D_i     = (const float*)d_in[10];
  const float* Tau_spk = (const float*)d_in[11];
  const float* W_spk   = (const float*)d_in[12];
  const float* W_hist  = (const float*)d_in[13];
  const float* Theta   = (const float*)d_in[14];

  float* out     = (float*)d_out;
  float* spk_out = out;            // 20000*16
  float* filt    = out + 320000;   // 64*200

  float* ws    = (float*)d_ws;
  float* syn_e = ws;               // 320000
  float* syn_i = ws + 320000;      // 320000
  float* synTh = ws + 640000;      // 320000  ([t][s] layout)

  filters_k<<<50, 256, 0, stream>>>(Tau_e, Tau_i, W_e, W_i, D_e, D_i,
                                    Tau_spk, W_spk, W_hist, filt);
  synmm_k<<<1250, 256, 0, stream>>>(S_e, C_syn_e, syn_e, E_NO_C);
  synmm_k<<<1250, 256, 0, stream>>>(S_i, C_syn_i, syn_i, I_NO_C);
  conv_k<<<1250, 256, 0, stream>>>(syn_e, syn_i, filt, Theta, synTh);
  scan9_k<<<1, 576, 0, stream>>>(synTh, filt, C_den, Tau_spk, W_spk, spk_out);
}

// Round 11
// 2487.663 us; speedup vs baseline: 1.1024x; 1.1024x over previous
//
#include <hip/hip_runtime.h>

#ifndef M_PI
#define M_PI 3.14159265358979323846
#endif

#define T_DATA 20000
#define E_NO_C 2000
#define I_NO_C 500
#define SUB 16
#define TNO 200
#define NGRP 5000   // 4-step groups

typedef float v2f __attribute__((ext_vector_type(2)));

// quad butterfly reduction on the VALU pipe (DPP quad_perm), no LDS traffic.
// 177 = quad_perm(1,0,3,2) [xor 1]; 78 = quad_perm(2,3,0,1) [xor 2].
__device__ __forceinline__ float quad_sum(float v) {
  int a = __builtin_amdgcn_mov_dpp(__float_as_int(v), 177, 0xf, 0xf, true);
  v += __int_as_float(a);
  int b = __builtin_amdgcn_mov_dpp(__float_as_int(v), 78, 0xf, 0xf, true);
  v += __int_as_float(b);
  return v;
}

// ---------------- Kernel A: filter kernels (e, i, spk, hist) -> d_out[320000..] ----------------
__global__ void filters_k(const float* __restrict__ Tau_e, const float* __restrict__ Tau_i,
                          const float* __restrict__ W_e,  const float* __restrict__ W_i,
                          const float* __restrict__ D_e,  const float* __restrict__ D_i,
                          const float* __restrict__ Tau_spk, const float* __restrict__ W_spk,
                          const float* __restrict__ W_hist,
                          float* __restrict__ filt_out) {
  int id = blockIdx.x * blockDim.x + threadIdx.x;
  if (id >= 64 * TNO) return;
  int r = id / TNO, x = id % TNO;
  int s = r & 15, kind = r >> 4;
  double xd = (double)x;
  double val;
  if (kind == 0) {
    double te = xd - exp((double)D_e[s]); te = te > 0.0 ? te : 0.0;
    double tt = te / exp((double)Tau_e[s]);
    val = tt * exp(-tt) * exp((double)W_e[s]);
  } else if (kind == 1) {
    double ti = xd - exp((double)D_i[s]); ti = ti > 0.0 ? ti : 0.0;
    double tt = ti / exp((double)Tau_i[s]);
    val = -tt * exp(-tt) * exp((double)W_i[s]);
  } else if (kind == 2) {
    double tt = xd / exp((double)Tau_spk[s]);
    val = tt * exp(-tt) * exp((double)W_spk[s]);
  } else {
    double raw = 4.0 * log(xd + 1.0);
    double acc = 0.0;
    for (int i = 0; i < 16; ++i) {
      double phi = (M_PI / 2.0) * (double)i;
      double b = (raw < phi - M_PI || raw > phi + M_PI) ? 0.0
                                                        : (0.5 * cos(raw - phi) + 0.5);
      acc += (double)W_hist[s * 16 + i] * b;
    }
    val = acc;
  }
  filt_out[id] = (float)val;
}

// ---------------- Kernel B: syn = S @ C^T, C staged in LDS tiles ----------------
#define ETILE 500
__global__ __launch_bounds__(256) void synmm_k(const float* __restrict__ S,
                                               const float* __restrict__ C,
                                               float* __restrict__ out, int E) {
  __shared__ __align__(16) float Cs[16][ETILE];
  int tid = threadIdx.x;
  int s = tid & 15, tt = tid >> 4;
  long t = (long)blockIdx.x * 16 + tt;
  const float* Srow = S + t * E;
  float acc = 0.f;
  for (int tb = 0; tb < E; tb += ETILE) {
    __syncthreads();
    for (int i = tid; i < 16 * ETILE; i += 256) {
      int s2 = i / ETILE, k2 = i - s2 * ETILE;
      Cs[s2][k2] = C[(long)s2 * E + tb + k2];
    }
    __syncthreads();
    const float* Crow = &Cs[s][0];
    const float* Sp = Srow + tb;
#pragma unroll 2
    for (int e = 0; e < ETILE; e += 4) {
      float4 a = *(const float4*)(Sp + e);
      float4 c = *(const float4*)(Crow + e);
      acc = fmaf(a.x, c.x, acc); acc = fmaf(a.y, c.y, acc);
      acc = fmaf(a.z, c.z, acc); acc = fmaf(a.w, c.w, acc);
    }
  }
  out[t * 16 + s] = acc;
}

// ---------------- Kernel C: causal depthwise conv + Theta, [t][s] layout ----------------
__global__ void conv_k(const float* __restrict__ syn_e, const float* __restrict__ syn_i,
                       const float* __restrict__ filt, const float* __restrict__ Theta,
                       float* __restrict__ synTh) {
  __shared__ float ek[16][201];
  __shared__ float ik[16][201];
  int tid = threadIdx.x;
  for (int idx = tid; idx < 16 * TNO; idx += 256) {
    ek[idx / TNO][idx % TNO] = filt[idx];
    ik[idx / TNO][idx % TNO] = filt[16 * TNO + idx];
  }
  __syncthreads();
  int s = tid & 15, tt = tid >> 4;
  int t = blockIdx.x * 16 + tt;
  float acc = Theta[s];
  if (t >= TNO) {
#pragma unroll 4
    for (int j = 0; j < TNO; ++j) {
      int u = t - 1 - j;
      acc += ek[s][j] * syn_e[u * 16 + s] + ik[s][j] * syn_i[u * 16 + s];
    }
  } else {
    for (int j = 0; j < t; ++j) {
      int u = t - 1 - j;
      acc += ek[s][j] * syn_e[u * 16 + s] + ik[s][j] * syn_i[u * 16 + s];
    }
  }
  synTh[t * 16 + s] = acc;
}

// ---------------- Kernel D: 9-wave pipeline, VALU (DPP) reductions, minimal LDS pipe ----------------
// Delay partition identical to R9 (verified, absmax 0): chain d=1; pend d<=3 in-group;
// carry S hidx 1..6; carry2 P hidx K+4..K+7; near hidx K+8..K+11; far hidx K+12..199.
// Changes vs R9: far waves lane-map (s=l>>2, qq=l&3), quad-DPP reduce, ONE b32 write;
// reduce wave lane-map (s,K): 6 b32 partial reads + near fma, one b32 write into merged
// farTotF (nearBuf gone); scan reads farTotF as a single b128. LDS-pipe ~740->~320 cyc/iter.
__global__ __launch_bounds__(576, 1) void scan10_k(const float* __restrict__ synTh,
                                                   const float* __restrict__ filt,
                                                   const float* __restrict__ C_den,
                                                   const float* __restrict__ Tau_spk,
                                                   const float* __restrict__ W_spk,
                                                   float* __restrict__ spk_out) {
  __shared__ __align__(16) float ring[16][452];       // [s][pos], mirror pos+256 for pos<192
  __shared__ __align__(16) float oPartF[3][6][64];    // [slot][farwave][4s+K]
  __shared__ __align__(16) float farTotF[2][64];      // [buf][4s+K]  (near folded in)
  __shared__ __align__(16) float synStage[2][4][16][20]; // [buf][g&3][s][K(+pad)]
  const int tid = threadIdx.x;
  const int widx = tid >> 6;
  const int l = tid & 63;
  const int s = l & 15, q = l >> 4;

  for (int i = tid; i < 16 * 452; i += 576) (&ring[0][0])[i] = 0.f;
  for (int i = tid; i < 3 * 6 * 64; i += 576) (&oPartF[0][0][0])[i] = 0.f;
  for (int i = tid; i < 2 * 64; i += 576) (&farTotF[0][0])[i] = 0.f;
  __syncthreads();
  if (widx == 2) {  // io: preload synTh groups 0..7
#pragma unroll
    for (int b2 = 0; b2 < 2; ++b2) {
      int e0 = b2 * 256 + 4 * l;
      float4 v = *(const float4*)&synTh[e0];
      int t0 = e0 >> 4, s0 = e0 & 15;
      int g = t0 >> 2, K = t0 & 3;
      synStage[(g >> 2) & 1][g & 3][s0 + 0][K] = v.x;
      synStage[(g >> 2) & 1][g & 3][s0 + 1][K] = v.y;
      synStage[(g >> 2) & 1][g & 3][s0 + 2][K] = v.z;
      synStage[(g >> 2) & 1][g & 3][s0 + 3][K] = v.w;
    }
  }
  __syncthreads();

  if (widx == 0) {
    // ================= scan wave =================
    const float* hrow = filt + (48 + s) * TNO;
    float hk[11];
#pragma unroll
    for (int i = 0; i < 11; ++i) hk[i] = hrow[i];

    float t0v = Tau_spk[0], w0v = W_spk[0];
    bool okrow = (Tau_spk[s] == t0v) && (W_spk[s] == w0v);
    unsigned cd = 0u;
#pragma unroll
    for (int j = 0; j < 16; ++j) {
      float cv = C_den[s * 16 + j];
      okrow = okrow && (cv == 0.f || cv == 1.f);
      cd |= (cv != 0.f) ? (1u << j) : 0u;
    }
    const bool uni = (bool)__all((int)okrow);

    const double tau  = exp((double)Tau_spk[s]);
    const double aa   = exp(-1.0 / tau);
    const double c2a  = exp((double)W_spk[s]) * aa / tau;  // K[d]=C(d-1)a^(d-1), C=w/tau
    const double twoa = 2.0 * aa;
    const double na2  = -aa * aa;

    double twoa4[4], na24[4], c2a4[4], yd0a[4], yd1a[4];
    float cden4[4];
#pragma unroll
    for (int r = 0; r < 4; ++r) {
      int j = 4 * q + r;
      double tj = exp((double)Tau_spk[j]);
      double aj = exp(-1.0 / tj);
      twoa4[r] = 2.0 * aj; na24[r] = -aj * aj;
      c2a4[r]  = exp((double)W_spk[j]) * aj / tj;
      yd0a[r] = 0.0; yd1a[r] = 0.0;
      cden4[r] = C_den[s * 16 + j];
    }

    double zA = 0.0, zB = 0.0;
    float mixu = 0.f, mix1 = 0.f;
    float P0 = 0.f, P1 = 0.f, P2 = 0.f, P3 = 0.f;   // prev group's spikes
    float sgPrev = 0.f;

    float4 syn0 = *(const float4*)&synStage[0][0][s][0];
    float oc0 = syn0.x, oc1 = syn0.y, oc2 = syn0.z, oc3 = syn0.w;

#define STEP(SGD, PRE, SGOUT)                                                 \
    {                                                                         \
      float sub = fmaf(hk[0], (SGD), (PRE));                                  \
      unsigned long long bal = __ballot(sub > 0.f);                           \
      float sg = sub > 0.f ? 1.f : 0.f;                                       \
      unsigned mk = (unsigned)bal & 0xFFFFu;                                  \
      if (uni) {                                                              \
        double zc = fma(twoa, zB, fma(na2, zA, c2a * (double)__popc(mk & cd))); \
        zA = zB; zB = zc;                                                     \
        mixu = (float)zA;                                                     \
      } else {                                                                \
        float p = 0.f;                                                        \
        _Pragma("unroll")                                                     \
        for (int r = 0; r < 4; ++r) {                                         \
          double xr = (double)((mk >> (4 * q + r)) & 1u);                     \
          double y2 = fma(twoa4[r], yd1a[r], fma(na24[r], yd0a[r], c2a4[r] * xr)); \
          yd0a[r] = yd1a[r]; yd1a[r] = y2;                                    \
          p = fmaf(cden4[r], (float)y2, p);                                   \
        }                                                                     \
        p += __shfl_xor(p, 16); p += __shfl_xor(p, 32);                       \
        float mixn = mix1; mix1 = p;                                          \
        mixu = mixn;                                                          \
      }                                                                       \
      (SGOUT) = sg;                                                           \
    }

    for (int n = 0; n < NGRP; ++n) {
      const int gn = n + 1;
      float4 farT = *(const float4*)&farTotF[gn & 1][4 * s];
      float4 synT = *(const float4*)&synStage[(gn >> 2) & 1][gn & 3][s][0];

      float S0, S1, S2, S3;
      STEP(sgPrev, oc0 + mixu, S0)
      float pend2 = hk[1] * S0;
      float pend3 = hk[2] * S0;
      STEP(S0, oc1 + mixu, S1)
      pend3 = fmaf(hk[1], S1, pend3);
      STEP(S1, (oc2 + mixu) + pend2, S2)
      STEP(S2, (oc3 + mixu) + pend3, S3)

      if (l < 16) {
        int u = (4 * n) & 255;
        float4 w0; w0.x = S0; w0.y = S1; w0.z = S2; w0.w = S3;
        *(float4*)&ring[s][u] = w0;
        if (u < 192) *(float4*)&ring[s][u + 256] = w0;
      }

      float c0 = fmaf(hk[1], S2, fmaf(hk[2], S1, hk[3] * S0));
      float c1 = fmaf(hk[1], S3, fmaf(hk[2], S2, fmaf(hk[3], S1, hk[4] * S0)));
      float c2 = fmaf(hk[2], S3, fmaf(hk[3], S2, fmaf(hk[4], S1, hk[5] * S0)));
      float c3 = fmaf(hk[3], S3, fmaf(hk[4], S2, fmaf(hk[5], S1, hk[6] * S0)));
      float cc0 = fmaf(hk[7], P0, fmaf(hk[6], P1, fmaf(hk[5], P2, hk[4] * P3)));
      float cc1 = fmaf(hk[8], P0, fmaf(hk[7], P1, fmaf(hk[6], P2, hk[5] * P3)));
      float cc2 = fmaf(hk[9], P0, fmaf(hk[8], P1, fmaf(hk[7], P2, hk[6] * P3)));
      float cc3 = fmaf(hk[10], P0, fmaf(hk[9], P1, fmaf(hk[8], P2, hk[7] * P3)));

      oc0 = (farT.x + (synT.x + c0)) + cc0;
      oc1 = (farT.y + (synT.y + c1)) + cc1;
      oc2 = (farT.z + (synT.z + c2)) + cc2;
      oc3 = (farT.w + (synT.w + c3)) + cc3;

      P0 = S0; P1 = S1; P2 = S2; P3 = S3;
      sgPrev = S3;
      __syncthreads();
    }
#undef STEP
  } else if (widx == 1) {
    // ================= near + reduce wave: lane = (s2 = l>>2, K = l&3) =================
    const int s2 = l >> 2, K = l & 3;
    const float* hrow = filt + (48 + s2) * TNO;
    const float hc0 = hrow[11 + K], hc1 = hrow[10 + K],
                hc2 = hrow[9 + K],  hc3 = hrow[8 + K];

    for (int n = 0; n < NGRP; ++n) {
      int We = (4 * n - 1) & 255;
      if (We < 191) We += 256;
      // near for group n+2: v = spikes(4n-4..4n-1), v.x at pos We-3
      float4 v = *(const float4*)&ring[s2][We - 3];
      float nr = hc3 * v.w;
      nr = fmaf(hc2, v.z, nr);
      nr = fmaf(hc1, v.y, nr);
      nr = fmaf(hc0, v.x, nr);
      // sum far partials for group n+2 (slot (n+2)%3, written by far waves at n-1)
      const int slot = (n + 2) % 3;
      float t0 = oPartF[slot][0][l] + oPartF[slot][1][l];
      float t1 = oPartF[slot][2][l] + oPartF[slot][3][l];
      float t2 = oPartF[slot][4][l] + oPartF[slot][5][l];
      farTotF[(n + 2) & 1][l] = nr + ((t0 + t1) + t2);
      __syncthreads();
    }
  } else if (widx == 2) {
    // ================= io wave: spk_out (batch 8), synStage (batch 4) =================
    for (int n = 0; n < NGRP; ++n) {
      if ((n & 3) == 2) {
        int g0 = n + 2;                       // g0 % 4 == 0
        if (g0 < NGRP) {
          int e0 = g0 * 64 + 4 * l;
          float4 v = *(const float4*)&synTh[e0];
          int t0 = e0 >> 4, s0 = e0 & 15;
          int g = t0 >> 2, K = t0 & 3;
          int buf = (g >> 2) & 1;
          synStage[buf][g & 3][s0 + 0][K] = v.x;
          synStage[buf][g & 3][s0 + 1][K] = v.y;
          synStage[buf][g & 3][s0 + 2][K] = v.z;
          synStage[buf][g & 3][s0 + 3][K] = v.w;
        }
      }
      if ((n & 7) == 0 && n > 0) {
        int We = (4 * n - 1) & 255;
        if (We < 191) We += 256;
        int base = We - 31;                   // times 4n-32..4n-1
#pragma unroll
        for (int r = 0; r < 2; ++r) {
          int e = 64 * (n - 8) + 256 * r + 4 * l;
          int t0 = e >> 4, s0 = e & 15;
          int pos = base + (t0 - 4 * (n - 8));
          float4 w;
          w.x = ring[s0 + 0][pos]; w.y = ring[s0 + 1][pos];
          w.z = ring[s0 + 2][pos]; w.w = ring[s0 + 3][pos];
          *(float4*)&spk_out[e] = w;
        }
      }
      __syncthreads();
    }
    {   // tail: groups NGRP-8..NGRP-1
      int n = NGRP;
      int We = (4 * n - 1) & 255;
      if (We < 191) We += 256;
      int base = We - 31;
#pragma unroll
      for (int r = 0; r < 2; ++r) {
        int e = 64 * (n - 8) + 256 * r + 4 * l;
        int t0 = e >> 4, s0 = e & 15;
        int pos = base + (t0 - 4 * (n - 8));
        float4 w;
        w.x = ring[s0 + 0][pos]; w.y = ring[s0 + 1][pos];
        w.z = ring[s0 + 2][pos]; w.w = ring[s0 + 3][pos];
        *(float4*)&spk_out[e] = w;
      }
    }
  } else {
    // ================= far waves f=0..5: lane = (s2, qq); group n+3, hidx >= K+12 =========
    const int f = widx - 3;
    const int s2 = l >> 2, qq = l & 3;
    const float* hrow = filt + (48 + s2) * TNO;
    const int base = 196 - 32 * f - 8 * qq;   // hidx for (i,K): base + (7-i) + K
    float ca[11];
#pragma unroll
    for (int m = 0; m < 11; ++m) {
      int hidx = base + m;
      ca[m] = (hidx <= 199) ? hrow[hidx] : 0.f;
    }
    v2f pr[11];
    pr[0].x = 0.f; pr[0].y = 0.f;
#pragma unroll
    for (int m = 1; m < 11; ++m) { pr[m].x = ca[m]; pr[m].y = ca[m - 1]; }

    for (int n = 0; n < NGRP; ++n) {
      int We = (4 * n - 1) & 255;
      if (We < 191) We += 256;
      const int Ws = We - 191;
      const float4* rp = (const float4*)&ring[s2][Ws + 32 * f + 8 * qq];
      float4 V0 = rp[0], V1 = rp[1];
      v2f p01, p23, p45, p67;
      p01.x = V0.x; p01.y = V0.y; p23.x = V0.z; p23.y = V0.w;
      p45.x = V1.x; p45.y = V1.y; p67.x = V1.z; p67.y = V1.w;
      float o0, o1, o2, o3;
      {
        v2f a = pr[7] * p01; a += pr[5] * p23; a += pr[3] * p45; a += pr[1] * p67;
        o0 = a.x + a.y;
      }
      {
        v2f a = pr[8] * p01; a += pr[6] * p23; a += pr[4] * p45; a += pr[2] * p67;
        o1 = a.x + a.y;
      }
      {
        v2f a = pr[9] * p01; a += pr[7] * p23; a += pr[5] * p45; a += pr[3] * p67;
        o2 = a.x + a.y;
      }
      {
        v2f a = pr[10] * p01; a += pr[8] * p23; a += pr[6] * p45; a += pr[4] * p67;
        o3 = a.x + a.y;
      }
      // reduce over qq (4 window chunks) on the VALU pipe
      o0 = quad_sum(o0); o1 = quad_sum(o1); o2 = quad_sum(o2); o3 = quad_sum(o3);
      float myo = (qq == 0) ? o0 : (qq == 1) ? o1 : (qq == 2) ? o2 : o3;
      oPartF[n % 3][f][l] = myo;   // one b32 per lane, conflict-free
      __syncthreads();
    }
  }
}

extern "C" void kernel_launch(void* const* d_in, const int* in_sizes, int n_in,
                              void* d_out, int out_size, void* d_ws, size_t ws_size,
                              hipStream_t stream) {
  const float* S_e     = (const float*)d_in[0];
  const float* S_i     = (const float*)d_in[1];
  const float* C_den   = (const float*)d_in[2];
  const float* C_syn_e = (const float*)d_in[3];
  const float* C_syn_i = (const float*)d_in[4];
  const float* Tau_e   = (const float*)d_in[5];
  const float* Tau_i   = (const float*)d_in[6];
  const float* W_e     = (const float*)d_in[7];
  const float* W_i     = (const float*)d_in[8];
  const float* D_e     = (const float*)d_in[9];
  const float* D_i     = (const float*)d_in[10];
  const float* Tau_spk = (const float*)d_in[11];
  const float* W_spk   = (const float*)d_in[12];
  const float* W_hist  = (const float*)d_in[13];
  const float* Theta   = (const float*)d_in[14];

  float* out     = (float*)d_out;
  float* spk_out = out;            // 20000*16
  float* filt    = out + 320000;   // 64*200

  float* ws    = (float*)d_ws;
  float* syn_e = ws;               // 320000
  float* syn_i = ws + 320000;      // 320000
  float* synTh = ws + 640000;      // 320000  ([t][s] layout)

  filters_k<<<50, 256, 0, stream>>>(Tau_e, Tau_i, W_e, W_i, D_e, D_i,
                                    Tau_spk, W_spk, W_hist, filt);
  synmm_k<<<1250, 256, 0, stream>>>(S_e, C_syn_e, syn_e, E_NO_C);
  synmm_k<<<1250, 256, 0, stream>>>(S_i, C_syn_i, syn_i, I_NO_C);
  conv_k<<<1250, 256, 0, stream>>>(syn_e, syn_i, filt, Theta, synTh);
  scan10_k<<<1, 576, 0, stream>>>(synTh, filt, C_den, Tau_spk, W_spk, spk_out);
}